// Round 2
// baseline (157.979 us; speedup 1.0000x reference)
//
#include <hip/hip_runtime.h>
#include <math.h>

#define ICC    196   // channels per point
#define CH     32    // channels staged per phase
#define NPHASE 6     // 6*32 = 192 staged channels (cells 0..191); tail 4 direct
#define PAD    261   // LDS row stride in floats (odd => ~2-way max on writes)

// One ReLU cell: z=[xi,y] -> Linear(2,6) -> ReLU -> Linear(6,1) -> ReLU
// W1 [cell][2][6], b1 [cell][6], W2 [cell][6], b2 [cell]
__device__ __forceinline__ float cell_step(float xi, float y, int i,
    const float* __restrict__ W1, const float* __restrict__ b1,
    const float* __restrict__ W2, const float* __restrict__ b2)
{
    const float* w1 = W1 + i * 12;
    const float* bb = b1 + i * 6;
    const float* w2 = W2 + i * 6;
    float h0 = fmaxf(fmaf(y, w1[6],  fmaf(xi, w1[0], bb[0])), 0.0f);
    float h1 = fmaxf(fmaf(y, w1[7],  fmaf(xi, w1[1], bb[1])), 0.0f);
    float h2 = fmaxf(fmaf(y, w1[8],  fmaf(xi, w1[2], bb[2])), 0.0f);
    float h3 = fmaxf(fmaf(y, w1[9],  fmaf(xi, w1[3], bb[3])), 0.0f);
    float h4 = fmaxf(fmaf(y, w1[10], fmaf(xi, w1[4], bb[4])), 0.0f);
    float h5 = fmaxf(fmaf(y, w1[11], fmaf(xi, w1[5], bb[5])), 0.0f);
    float a0 = fmaf(h0, w2[0], fmaf(h1, w2[1], b2[i]));
    float a1 = fmaf(h2, w2[2], h3 * w2[3]);
    float a2 = fmaf(h4, w2[4], h5 * w2[5]);
    return fmaxf(a0 + (a1 + a2), 0.0f);
}

__global__ __launch_bounds__(256, 4) void rnn_kernel(
    const float* __restrict__ x,    // [P, 196]
    const float* __restrict__ W1,   // [195, 2, 6]
    const float* __restrict__ b1,   // [195, 6]
    const float* __restrict__ W2,   // [195, 6]
    const float* __restrict__ b2,   // [195]
    const float* __restrict__ Wf1,  // [2, 6]
    const float* __restrict__ bf1,  // [6]
    const float* __restrict__ Wf2,  // [6]
    const float* __restrict__ bf2,  // [1]
    float* __restrict__ out,        // [P]
    int npoints)
{
    __shared__ float lds[CH * PAD];   // transposed tile: lds[ch*PAD + pt]

    const int tid = threadIdx.x;
    const int p0  = blockIdx.x * 256;
    const int p   = p0 + tid;

    // cooperative-load mapping: thread t, rep k -> point (t>>3)+32k, channels 4*(t&7)..+3
    const int ch0 = (tid & 7) * 4;
    const int ptb = tid >> 3;

    float4 rA[8];   // staged chunk (next phase), 32 VGPRs

    // tail channels 192..195 for this thread's own point — issue now, use at the end
    const int pc_self = (p < npoints) ? p : (npoints - 1);
    const float4 tail = *reinterpret_cast<const float4*>(
        x + (size_t)pc_self * ICC + 192);

    // ---- prologue: load chunk 0, write it, start chunk 1 ----
    #pragma unroll
    for (int k = 0; k < 8; ++k) {
        int pt = ptb + 32 * k;
        int pc = p0 + pt; if (pc >= npoints) pc = npoints - 1;
        rA[k] = *reinterpret_cast<const float4*>(x + (size_t)pc * ICC + 0 * CH + ch0);
    }
    #pragma unroll
    for (int k = 0; k < 8; ++k) {
        int pt = ptb + 32 * k;
        lds[(ch0 + 0) * PAD + pt] = rA[k].x;
        lds[(ch0 + 1) * PAD + pt] = rA[k].y;
        lds[(ch0 + 2) * PAD + pt] = rA[k].z;
        lds[(ch0 + 3) * PAD + pt] = rA[k].w;
    }
    #pragma unroll
    for (int k = 0; k < 8; ++k) {
        int pt = ptb + 32 * k;
        int pc = p0 + pt; if (pc >= npoints) pc = npoints - 1;
        rA[k] = *reinterpret_cast<const float4*>(x + (size_t)pc * ICC + 1 * CH + ch0);
    }
    __syncthreads();

    float y = lds[tid];   // y0 = channel 0 of own point

    // ---- main pipeline: compute phase c while phase c+2 loads fly ----
    #pragma unroll 1
    for (int c = 0; c < NPHASE; ++c) {
        #pragma unroll
        for (int j = 0; j < CH; ++j) {
            float xi = lds[j * PAD + tid];
            y = cell_step(xi, y, c * CH + j, W1, b1, W2, b2);
        }
        if (c < NPHASE - 1) {
            __syncthreads();              // all readers done with current tile
            #pragma unroll
            for (int k = 0; k < 8; ++k) { // write chunk c+1 (waits vmcnt)
                int pt = ptb + 32 * k;
                lds[(ch0 + 0) * PAD + pt] = rA[k].x;
                lds[(ch0 + 1) * PAD + pt] = rA[k].y;
                lds[(ch0 + 2) * PAD + pt] = rA[k].z;
                lds[(ch0 + 3) * PAD + pt] = rA[k].w;
            }
            if (c < NPHASE - 2) {         // issue chunk c+2
                #pragma unroll
                for (int k = 0; k < 8; ++k) {
                    int pt = ptb + 32 * k;
                    int pc = p0 + pt; if (pc >= npoints) pc = npoints - 1;
                    rA[k] = *reinterpret_cast<const float4*>(
                        x + (size_t)pc * ICC + (c + 2) * CH + ch0);
                }
            }
            __syncthreads();
        }
    }

    // ---- tail: cells 192..194 + final sigmoid cell (channel 195) ----
    y = cell_step(tail.x, y, 192, W1, b1, W2, b2);
    y = cell_step(tail.y, y, 193, W1, b1, W2, b2);
    y = cell_step(tail.z, y, 194, W1, b1, W2, b2);

    const float xf = tail.w;
    float t = bf2[0];
    float hf0 = fmaxf(fmaf(y, Wf1[6],  fmaf(xf, Wf1[0], bf1[0])), 0.0f);
    float hf1 = fmaxf(fmaf(y, Wf1[7],  fmaf(xf, Wf1[1], bf1[1])), 0.0f);
    float hf2 = fmaxf(fmaf(y, Wf1[8],  fmaf(xf, Wf1[2], bf1[2])), 0.0f);
    float hf3 = fmaxf(fmaf(y, Wf1[9],  fmaf(xf, Wf1[3], bf1[3])), 0.0f);
    float hf4 = fmaxf(fmaf(y, Wf1[10], fmaf(xf, Wf1[4], bf1[4])), 0.0f);
    float hf5 = fmaxf(fmaf(y, Wf1[11], fmaf(xf, Wf1[5], bf1[5])), 0.0f);
    float a0 = fmaf(hf0, Wf2[0], fmaf(hf1, Wf2[1], t));
    float a1 = fmaf(hf2, Wf2[2], hf3 * Wf2[3]);
    float a2 = fmaf(hf4, Wf2[4], hf5 * Wf2[5]);
    t = a0 + (a1 + a2);

    if (p < npoints)
        out[p] = 1.0f / (1.0f + __expf(-t));
}

extern "C" void kernel_launch(void* const* d_in, const int* in_sizes, int n_in,
                              void* d_out, int out_size, void* d_ws, size_t ws_size,
                              hipStream_t stream) {
    const float* x   = (const float*)d_in[0];
    const float* W1  = (const float*)d_in[1];
    const float* b1  = (const float*)d_in[2];
    const float* W2  = (const float*)d_in[3];
    const float* b2  = (const float*)d_in[4];
    const float* Wf1 = (const float*)d_in[5];
    const float* bf1 = (const float*)d_in[6];
    const float* Wf2 = (const float*)d_in[7];
    const float* bf2 = (const float*)d_in[8];
    float* out = (float*)d_out;

    const int npoints = out_size;                 // B*N = 262144
    const int block = 256;
    const int grid = (npoints + block - 1) / block;
    rnn_kernel<<<grid, block, 0, stream>>>(x, W1, b1, W2, b2,
                                           Wf1, bf1, Wf2, bf2, out, npoints);
}

// Round 3
// 132.629 us; speedup vs baseline: 1.1911x; 1.1911x over previous
//
#include <hip/hip_runtime.h>
#include <math.h>

#define ICC   196   // channels per point
#define CH    16    // channels staged per phase
#define NPH   12    // 12*16 = 192 staged channels (cells 0..191); tail 4 direct
#define RS    17    // LDS row stride in floats (odd -> 2-way banks = free)
#define PTS   512   // points per block (256 threads x P=2)

typedef float f32x2 __attribute__((ext_vector_type(2)));

__device__ __forceinline__ f32x2 sp(float s) { f32x2 r; r.x = s; r.y = s; return r; }
__device__ __forceinline__ f32x2 efma(f32x2 a, f32x2 b, f32x2 c) {
    return __builtin_elementwise_fma(a, b, c);
}
__device__ __forceinline__ f32x2 emax0(f32x2 a) {
    return __builtin_elementwise_max(a, sp(0.0f));
}

// One ReLU cell for TWO independent points packed in f32x2.
// W1 [cell][2][6], b1 [cell][6], W2 [cell][6], b2 [cell]
__device__ __forceinline__ f32x2 cell_step2(f32x2 xi, f32x2 y, int i,
    const float* __restrict__ W1, const float* __restrict__ b1,
    const float* __restrict__ W2, const float* __restrict__ b2)
{
    const float* w1 = W1 + i * 12;
    const float* bb = b1 + i * 6;
    const float* w2 = W2 + i * 6;
    f32x2 h0 = emax0(efma(y, sp(w1[6]),  efma(xi, sp(w1[0]), sp(bb[0]))));
    f32x2 h1 = emax0(efma(y, sp(w1[7]),  efma(xi, sp(w1[1]), sp(bb[1]))));
    f32x2 h2 = emax0(efma(y, sp(w1[8]),  efma(xi, sp(w1[2]), sp(bb[2]))));
    f32x2 h3 = emax0(efma(y, sp(w1[9]),  efma(xi, sp(w1[3]), sp(bb[3]))));
    f32x2 h4 = emax0(efma(y, sp(w1[10]), efma(xi, sp(w1[4]), sp(bb[4]))));
    f32x2 h5 = emax0(efma(y, sp(w1[11]), efma(xi, sp(w1[5]), sp(bb[5]))));
    f32x2 a0 = efma(h0, sp(w2[0]), efma(h1, sp(w2[1]), sp(b2[i])));
    f32x2 a1 = efma(h2, sp(w2[2]), h3 * sp(w2[3]));
    f32x2 a2 = efma(h4, sp(w2[4]), h5 * sp(w2[5]));
    return emax0(a0 + (a1 + a2));
}

__device__ __forceinline__ float final_cell(float xf, float y,
    const float* __restrict__ Wf1, const float* __restrict__ bf1,
    const float* __restrict__ Wf2, const float* __restrict__ bf2)
{
    float h0 = fmaxf(fmaf(y, Wf1[6],  fmaf(xf, Wf1[0], bf1[0])), 0.0f);
    float h1 = fmaxf(fmaf(y, Wf1[7],  fmaf(xf, Wf1[1], bf1[1])), 0.0f);
    float h2 = fmaxf(fmaf(y, Wf1[8],  fmaf(xf, Wf1[2], bf1[2])), 0.0f);
    float h3 = fmaxf(fmaf(y, Wf1[9],  fmaf(xf, Wf1[3], bf1[3])), 0.0f);
    float h4 = fmaxf(fmaf(y, Wf1[10], fmaf(xf, Wf1[4], bf1[4])), 0.0f);
    float h5 = fmaxf(fmaf(y, Wf1[11], fmaf(xf, Wf1[5], bf1[5])), 0.0f);
    float a0 = fmaf(h0, Wf2[0], fmaf(h1, Wf2[1], bf2[0]));
    float a1 = fmaf(h2, Wf2[2], h3 * Wf2[3]);
    float a2 = fmaf(h4, Wf2[4], h5 * Wf2[5]);
    float t = a0 + (a1 + a2);
    return 1.0f / (1.0f + __expf(-t));
}

__global__ __launch_bounds__(256, 2) void rnn_kernel(
    const float* __restrict__ x,    // [P, 196]
    const float* __restrict__ W1,   // [195, 2, 6]
    const float* __restrict__ b1,   // [195, 6]
    const float* __restrict__ W2,   // [195, 6]
    const float* __restrict__ b2,   // [195]
    const float* __restrict__ Wf1,  // [2, 6]
    const float* __restrict__ bf1,  // [6]
    const float* __restrict__ Wf2,  // [6]
    const float* __restrict__ bf2,  // [1]
    float* __restrict__ out,        // [P]
    int npoints)
{
    __shared__ float lds[PTS * RS];     // [512 rows][17], phase-local channels 0..15

    const int tid = threadIdx.x;
    const int p0  = blockIdx.x * PTS;
    const int pA  = p0 + tid;           // this thread's two points
    const int pB  = p0 + 256 + tid;

    // cooperative-load mapping: 512 rows x 4 float4-chunks per phase.
    // lane t, sweep k: row rl=(t>>2)+64k, chunk q=(t&3) -> channels 4q..4q+3.
    const int rl0 = tid >> 2;
    const int q4  = (tid & 3) * 4;

    float4 rA[8];

    // tail channels 192..195 of both points, issued now, used at the very end
    const int pAc = (pA < npoints) ? pA : (npoints - 1);
    const int pBc = (pB < npoints) ? pB : (npoints - 1);
    const float4 tailA = *reinterpret_cast<const float4*>(x + (size_t)pAc * ICC + 192);
    const float4 tailB = *reinterpret_cast<const float4*>(x + (size_t)pBc * ICC + 192);

    // ---- prologue: load chunk 0, write it, start chunk 1 ----
    #pragma unroll
    for (int k = 0; k < 8; ++k) {
        int rl = rl0 + 64 * k;
        int pc = p0 + rl; if (pc >= npoints) pc = npoints - 1;
        rA[k] = *reinterpret_cast<const float4*>(x + (size_t)pc * ICC + 0 * CH + q4);
    }
    #pragma unroll
    for (int k = 0; k < 8; ++k) {
        int rl = rl0 + 64 * k;
        lds[rl * RS + q4 + 0] = rA[k].x;
        lds[rl * RS + q4 + 1] = rA[k].y;
        lds[rl * RS + q4 + 2] = rA[k].z;
        lds[rl * RS + q4 + 3] = rA[k].w;
    }
    #pragma unroll
    for (int k = 0; k < 8; ++k) {
        int rl = rl0 + 64 * k;
        int pc = p0 + rl; if (pc >= npoints) pc = npoints - 1;
        rA[k] = *reinterpret_cast<const float4*>(x + (size_t)pc * ICC + 1 * CH + q4);
    }
    __syncthreads();

    // y0 = channel 0 of each point
    f32x2 y;
    y.x = lds[tid * RS + 0];
    y.y = lds[(tid + 256) * RS + 0];

    // ---- main pipeline: compute phase c; phase c+1 staged in regs; c+2 loads fly ----
    #pragma unroll 1
    for (int c = 0; c < NPH; ++c) {
        #pragma unroll
        for (int j = 0; j < CH; ++j) {
            f32x2 xi;
            xi.x = lds[tid * RS + j];
            xi.y = lds[(tid + 256) * RS + j];
            y = cell_step2(xi, y, c * CH + j, W1, b1, W2, b2);
        }
        if (c < NPH - 1) {
            __syncthreads();                  // readers done with current tile
            #pragma unroll
            for (int k = 0; k < 8; ++k) {     // write chunk c+1 (waits vmcnt)
                int rl = rl0 + 64 * k;
                lds[rl * RS + q4 + 0] = rA[k].x;
                lds[rl * RS + q4 + 1] = rA[k].y;
                lds[rl * RS + q4 + 2] = rA[k].z;
                lds[rl * RS + q4 + 3] = rA[k].w;
            }
            if (c < NPH - 2) {                // issue chunk c+2
                #pragma unroll
                for (int k = 0; k < 8; ++k) {
                    int rl = rl0 + 64 * k;
                    int pc = p0 + rl; if (pc >= npoints) pc = npoints - 1;
                    rA[k] = *reinterpret_cast<const float4*>(
                        x + (size_t)pc * ICC + (c + 2) * CH + q4);
                }
            }
            __syncthreads();
        }
    }

    // ---- tail: cells 192..194 packed, then final sigmoid cell per point ----
    f32x2 xt;
    xt.x = tailA.x; xt.y = tailB.x;
    y = cell_step2(xt, y, 192, W1, b1, W2, b2);
    xt.x = tailA.y; xt.y = tailB.y;
    y = cell_step2(xt, y, 193, W1, b1, W2, b2);
    xt.x = tailA.z; xt.y = tailB.z;
    y = cell_step2(xt, y, 194, W1, b1, W2, b2);

    if (pA < npoints)
        out[pA] = final_cell(tailA.w, y.x, Wf1, bf1, Wf2, bf2);
    if (pB < npoints)
        out[pB] = final_cell(tailB.w, y.y, Wf1, bf1, Wf2, bf2);
}

extern "C" void kernel_launch(void* const* d_in, const int* in_sizes, int n_in,
                              void* d_out, int out_size, void* d_ws, size_t ws_size,
                              hipStream_t stream) {
    const float* x   = (const float*)d_in[0];
    const float* W1  = (const float*)d_in[1];
    const float* b1  = (const float*)d_in[2];
    const float* W2  = (const float*)d_in[3];
    const float* b2  = (const float*)d_in[4];
    const float* Wf1 = (const float*)d_in[5];
    const float* bf1 = (const float*)d_in[6];
    const float* Wf2 = (const float*)d_in[7];
    const float* bf2 = (const float*)d_in[8];
    float* out = (float*)d_out;

    const int npoints = out_size;                     // B*N = 262144
    const int grid = (npoints + PTS - 1) / PTS;       // 512 blocks
    rnn_kernel<<<grid, 256, 0, stream>>>(x, W1, b1, W2, b2,
                                         Wf1, bf1, Wf2, bf2, out, npoints);
}

// Round 4
// 104.567 us; speedup vs baseline: 1.5108x; 1.2684x over previous
//
#include <hip/hip_runtime.h>
#include <math.h>

#define ICC 196   // channels per point
#define CH  16    // channels staged per phase
#define NPH 12    // 12*16 = 192 staged channels (cells 0..191); tail 4 direct
#define RS  257   // LDS tile row stride in floats ([ch][pt], odd -> conflict-free reads)
#define BLK 256   // threads per block == points per block

// One ReLU cell: z=[xi,y] -> Linear(2,6) -> ReLU -> Linear(6,1) -> ReLU
// W1 [cell][2][6], b1 [cell][6], W2 [cell][6], b2 [cell]. Weights are
// wave-uniform -> compiler uses s_load (SMEM); xi/y live in VGPRs.
__device__ __forceinline__ float cell_step(float xi, float y, int i,
    const float* __restrict__ W1, const float* __restrict__ b1,
    const float* __restrict__ W2, const float* __restrict__ b2)
{
    const float* w1 = W1 + i * 12;
    const float* bb = b1 + i * 6;
    const float* w2 = W2 + i * 6;
    float h0 = fmaxf(fmaf(y, w1[6],  fmaf(xi, w1[0], bb[0])), 0.0f);
    float h1 = fmaxf(fmaf(y, w1[7],  fmaf(xi, w1[1], bb[1])), 0.0f);
    float h2 = fmaxf(fmaf(y, w1[8],  fmaf(xi, w1[2], bb[2])), 0.0f);
    float h3 = fmaxf(fmaf(y, w1[9],  fmaf(xi, w1[3], bb[3])), 0.0f);
    float h4 = fmaxf(fmaf(y, w1[10], fmaf(xi, w1[4], bb[4])), 0.0f);
    float h5 = fmaxf(fmaf(y, w1[11], fmaf(xi, w1[5], bb[5])), 0.0f);
    float a0 = fmaf(h0, w2[0], fmaf(h1, w2[1], b2[i]));
    float a1 = fmaf(h2, w2[2], h3 * w2[3]);
    float a2 = fmaf(h4, w2[4], h5 * w2[5]);
    return fmaxf(a0 + (a1 + a2), 0.0f);
}

__global__ __launch_bounds__(BLK, 4) void rnn_kernel(
    const float* __restrict__ x,    // [P, 196]
    const float* __restrict__ W1,   // [195, 2, 6]
    const float* __restrict__ b1,   // [195, 6]
    const float* __restrict__ W2,   // [195, 6]
    const float* __restrict__ b2,   // [195]
    const float* __restrict__ Wf1,  // [2, 6]
    const float* __restrict__ bf1,  // [6]
    const float* __restrict__ Wf2,  // [6]
    const float* __restrict__ bf2,  // [1]
    float* __restrict__ out,        // [P]
    int npoints)
{
    __shared__ float tile[CH * RS];   // transposed: tile[ch*RS + pt]

    const int tid = threadIdx.x;
    const int p0  = blockIdx.x * BLK;
    const int p   = p0 + tid;

    // cooperative staging: thread t, sweep k -> row (t>>2)+64k, channels 4*(t&3)..+3
    // 4 consecutive lanes cover a 64B-contiguous run of one row -> coalesced.
    const int rl0 = tid >> 2;
    const int q4  = (tid & 3) * 4;

    float4 rA[4];   // next phase's staged chunk (16 VGPRs)

    // tail channels 192..195 of own point: issue now, consume at the end (vmcnt)
    const int pc_self = (p < npoints) ? p : (npoints - 1);
    const float4 tail = *reinterpret_cast<const float4*>(
        x + (size_t)pc_self * ICC + 192);

    // ---- prologue: load+write phase 0, start loads for phase 1 ----
    #pragma unroll
    for (int k = 0; k < 4; ++k) {
        int rl = rl0 + 64 * k;
        int pc = p0 + rl; if (pc >= npoints) pc = npoints - 1;
        rA[k] = *reinterpret_cast<const float4*>(x + (size_t)pc * ICC + 0 * CH + q4);
    }
    #pragma unroll
    for (int k = 0; k < 4; ++k) {
        int rl = rl0 + 64 * k;
        tile[(q4 + 0) * RS + rl] = rA[k].x;
        tile[(q4 + 1) * RS + rl] = rA[k].y;
        tile[(q4 + 2) * RS + rl] = rA[k].z;
        tile[(q4 + 3) * RS + rl] = rA[k].w;
    }
    #pragma unroll
    for (int k = 0; k < 4; ++k) {
        int rl = rl0 + 64 * k;
        int pc = p0 + rl; if (pc >= npoints) pc = npoints - 1;
        rA[k] = *reinterpret_cast<const float4*>(x + (size_t)pc * ICC + 1 * CH + q4);
    }
    __syncthreads();

    float y = tile[0 * RS + tid];   // y0 = channel 0 of own point

    // ---- main loop: per phase, slurp xi into regs (one lgkmcnt drain),
    //      restage LDS for c+1, launch loads for c+2, then a pure
    //      VALU+SMEM 16-cell burst with zero DS ops. ----
    #pragma unroll 1
    for (int c = 0; c < NPH; ++c) {
        float xi[CH];
        #pragma unroll
        for (int j = 0; j < CH; ++j)
            xi[j] = tile[j * RS + tid];      // stride-1 lanes: conflict-free

        if (c < NPH - 1) {
            __syncthreads();                 // everyone's xi reads are done
            #pragma unroll
            for (int k = 0; k < 4; ++k) {    // write phase c+1 (waits vmcnt on rA)
                int rl = rl0 + 64 * k;
                tile[(q4 + 0) * RS + rl] = rA[k].x;
                tile[(q4 + 1) * RS + rl] = rA[k].y;
                tile[(q4 + 2) * RS + rl] = rA[k].z;
                tile[(q4 + 3) * RS + rl] = rA[k].w;
            }
            if (c < NPH - 2) {               // issue phase c+2 loads (fly over compute)
                #pragma unroll
                for (int k = 0; k < 4; ++k) {
                    int rl = rl0 + 64 * k;
                    int pc = p0 + rl; if (pc >= npoints) pc = npoints - 1;
                    rA[k] = *reinterpret_cast<const float4*>(
                        x + (size_t)pc * ICC + (c + 2) * CH + q4);
                }
            }
            __syncthreads();                 // tile(c+1) ready
        }

        #pragma unroll
        for (int j = 0; j < CH; ++j)
            y = cell_step(xi[j], y, c * CH + j, W1, b1, W2, b2);
    }

    // ---- tail: cells 192..194, then the final sigmoid cell (channel 195) ----
    y = cell_step(tail.x, y, 192, W1, b1, W2, b2);
    y = cell_step(tail.y, y, 193, W1, b1, W2, b2);
    y = cell_step(tail.z, y, 194, W1, b1, W2, b2);

    const float xf = tail.w;
    float h0 = fmaxf(fmaf(y, Wf1[6],  fmaf(xf, Wf1[0], bf1[0])), 0.0f);
    float h1 = fmaxf(fmaf(y, Wf1[7],  fmaf(xf, Wf1[1], bf1[1])), 0.0f);
    float h2 = fmaxf(fmaf(y, Wf1[8],  fmaf(xf, Wf1[2], bf1[2])), 0.0f);
    float h3 = fmaxf(fmaf(y, Wf1[9],  fmaf(xf, Wf1[3], bf1[3])), 0.0f);
    float h4 = fmaxf(fmaf(y, Wf1[10], fmaf(xf, Wf1[4], bf1[4])), 0.0f);
    float h5 = fmaxf(fmaf(y, Wf1[11], fmaf(xf, Wf1[5], bf1[5])), 0.0f);
    float a0 = fmaf(h0, Wf2[0], fmaf(h1, Wf2[1], bf2[0]));
    float a1 = fmaf(h2, Wf2[2], h3 * Wf2[3]);
    float a2 = fmaf(h4, Wf2[4], h5 * Wf2[5]);
    float t  = a0 + (a1 + a2);

    if (p < npoints)
        out[p] = 1.0f / (1.0f + __expf(-t));
}

extern "C" void kernel_launch(void* const* d_in, const int* in_sizes, int n_in,
                              void* d_out, int out_size, void* d_ws, size_t ws_size,
                              hipStream_t stream) {
    const float* x   = (const float*)d_in[0];
    const float* W1  = (const float*)d_in[1];
    const float* b1  = (const float*)d_in[2];
    const float* W2  = (const float*)d_in[3];
    const float* b2  = (const float*)d_in[4];
    const float* Wf1 = (const float*)d_in[5];
    const float* bf1 = (const float*)d_in[6];
    const float* Wf2 = (const float*)d_in[7];
    const float* bf2 = (const float*)d_in[8];
    float* out = (float*)d_out;

    const int npoints = out_size;                 // B*N = 262144
    const int grid = (npoints + BLK - 1) / BLK;   // 1024 blocks -> 4/CU, 16 waves/CU
    rnn_kernel<<<grid, BLK, 0, stream>>>(x, W1, b1, W2, b2,
                                         Wf1, bf1, Wf2, bf2, out, npoints);
}

// Round 5
// 88.875 us; speedup vs baseline: 1.7776x; 1.1766x over previous
//
#include <hip/hip_runtime.h>
#include <math.h>

#define ICC 196   // channels per point
#define CH  16    // channels staged per phase
#define NPH 12    // 12*16 = 192 staged channels (cells 0..191); tail 4 direct
#define RS  260   // LDS row stride (dwords): writes land exactly 2 lanes/bank = free
#define BLK 256   // threads per block == points per block

// liveness pins: force value into a register at this point (defeats load sinking)
#define PINV(x) asm volatile("" : "+v"(x))
#define PINS(x) asm volatile("" : "+s"(x))

// one cell's weights in named scalar fields (wave-uniform -> SGPRs)
struct Wc {
    float a0,a1,a2,a3,a4,a5,a6,a7,a8,a9,a10,a11;  // W1 [2][6] row-major
    float c0,c1,c2,c3,c4,c5;                       // b1
    float d0,d1,d2,d3,d4,d5;                       // W2
    float e0;                                      // b2
};

__device__ __forceinline__ Wc loadW(int i,
    const float* __restrict__ W1, const float* __restrict__ b1,
    const float* __restrict__ W2, const float* __restrict__ b2)
{
    Wc w;
    const float* p = W1 + i * 12;
    w.a0=p[0]; w.a1=p[1]; w.a2=p[2];  w.a3=p[3];  w.a4=p[4];  w.a5=p[5];
    w.a6=p[6]; w.a7=p[7]; w.a8=p[8];  w.a9=p[9];  w.a10=p[10]; w.a11=p[11];
    const float* q = b1 + i * 6;
    w.c0=q[0]; w.c1=q[1]; w.c2=q[2]; w.c3=q[3]; w.c4=q[4]; w.c5=q[5];
    const float* r = W2 + i * 6;
    w.d0=r[0]; w.d1=r[1]; w.d2=r[2]; w.d3=r[3]; w.d4=r[4]; w.d5=r[5];
    w.e0 = b2[i];
    return w;
}

__device__ __forceinline__ void pinW(Wc& w) {
    PINS(w.a0); PINS(w.a1); PINS(w.a2);  PINS(w.a3);  PINS(w.a4);  PINS(w.a5);
    PINS(w.a6); PINS(w.a7); PINS(w.a8);  PINS(w.a9);  PINS(w.a10); PINS(w.a11);
    PINS(w.c0); PINS(w.c1); PINS(w.c2);  PINS(w.c3);  PINS(w.c4);  PINS(w.c5);
    PINS(w.d0); PINS(w.d1); PINS(w.d2);  PINS(w.d3);  PINS(w.d4);  PINS(w.d5);
    PINS(w.e0);
}

// z=[xi,y] -> Linear(2,6) -> ReLU -> Linear(6,1) -> ReLU, weights pre-pinned
__device__ __forceinline__ float cellW(float xi, float y, const Wc& w)
{
    float h0 = fmaxf(fmaf(y, w.a6,  fmaf(xi, w.a0, w.c0)), 0.0f);
    float h1 = fmaxf(fmaf(y, w.a7,  fmaf(xi, w.a1, w.c1)), 0.0f);
    float h2 = fmaxf(fmaf(y, w.a8,  fmaf(xi, w.a2, w.c2)), 0.0f);
    float h3 = fmaxf(fmaf(y, w.a9,  fmaf(xi, w.a3, w.c3)), 0.0f);
    float h4 = fmaxf(fmaf(y, w.a10, fmaf(xi, w.a4, w.c4)), 0.0f);
    float h5 = fmaxf(fmaf(y, w.a11, fmaf(xi, w.a5, w.c5)), 0.0f);
    float s0 = fmaf(h0, w.d0, fmaf(h1, w.d1, w.e0));
    float s1 = fmaf(h2, w.d2, h3 * w.d3);
    float s2 = fmaf(h4, w.d4, h5 * w.d5);
    return fmaxf(s0 + (s1 + s2), 0.0f);
}

__global__ __launch_bounds__(BLK, 4) void rnn_kernel(
    const float* __restrict__ x,    // [P, 196]
    const float* __restrict__ W1,   // [195, 2, 6]
    const float* __restrict__ b1,   // [195, 6]
    const float* __restrict__ W2,   // [195, 6]
    const float* __restrict__ b2,   // [195]
    const float* __restrict__ Wf1,  // [2, 6]
    const float* __restrict__ bf1,  // [6]
    const float* __restrict__ Wf2,  // [6]
    const float* __restrict__ bf2,  // [1]
    float* __restrict__ out,        // [P]
    int npoints)
{
    __shared__ float tile[CH * RS];   // transposed: tile[ch*RS + pt]

    const int tid = threadIdx.x;
    const int p0  = blockIdx.x * BLK;
    const int p   = p0 + tid;

    // staging map: thread t, sweep k -> row (t>>2)+64k, channels 4*(t&3)..+3
    const int rl0 = tid >> 2;
    const int q4  = (tid & 3) * 4;

    float4 rA[4];   // next phase's staged chunk

    // tail channels 192..195 of own point (vmcnt; oldest in flight, lands early)
    const int pc_self = (p < npoints) ? p : (npoints - 1);
    const float4 tail = *reinterpret_cast<const float4*>(
        x + (size_t)pc_self * ICC + 192);

    // ---- prologue: load+write phase 0, start loads for phase 1 ----
    #pragma unroll
    for (int k = 0; k < 4; ++k) {
        int rl = rl0 + 64 * k;
        int pc = p0 + rl; if (pc >= npoints) pc = npoints - 1;
        rA[k] = *reinterpret_cast<const float4*>(x + (size_t)pc * ICC + 0 * CH + q4);
    }
    #pragma unroll
    for (int k = 0; k < 4; ++k) {
        int rl = rl0 + 64 * k;
        tile[(q4 + 0) * RS + rl] = rA[k].x;
        tile[(q4 + 1) * RS + rl] = rA[k].y;
        tile[(q4 + 2) * RS + rl] = rA[k].z;
        tile[(q4 + 3) * RS + rl] = rA[k].w;
    }
    #pragma unroll
    for (int k = 0; k < 4; ++k) {
        int rl = rl0 + 64 * k;
        int pc = p0 + rl; if (pc >= npoints) pc = npoints - 1;
        rA[k] = *reinterpret_cast<const float4*>(x + (size_t)pc * ICC + 1 * CH + q4);
    }
    __syncthreads();

    float y = tile[0 * RS + tid];   // y0 = channel 0 of own point

    // ---- main loop ----
    #pragma unroll 1
    for (int c = 0; c < NPH; ++c) {
        // issue first cell's weight loads early (lands during xi reads / barrier)
        Wc wc = loadW(c * CH, W1, b1, W2, b2);

        // slurp this phase's xi into VGPRs and PIN them there:
        // the compute burst below then has ZERO ds ops.
        float xi[CH];
        #pragma unroll
        for (int j = 0; j < CH; ++j)
            xi[j] = tile[j * RS + tid];       // lanes stride-1: conflict-free
        #pragma unroll
        for (int j = 0; j < CH; ++j)
            PINV(xi[j]);

        pinW(wc);

        if (c < NPH - 1) {
            __syncthreads();                  // everyone's xi reads are done
            #pragma unroll
            for (int k = 0; k < 4; ++k) {     // write phase c+1 (waits vmcnt on rA)
                int rl = rl0 + 64 * k;
                tile[(q4 + 0) * RS + rl] = rA[k].x;
                tile[(q4 + 1) * RS + rl] = rA[k].y;
                tile[(q4 + 2) * RS + rl] = rA[k].z;
                tile[(q4 + 3) * RS + rl] = rA[k].w;
            }
            if (c < NPH - 2) {                // issue phase c+2 loads
                #pragma unroll
                for (int k = 0; k < 4; ++k) {
                    int rl = rl0 + 64 * k;
                    int pc = p0 + rl; if (pc >= npoints) pc = npoints - 1;
                    rA[k] = *reinterpret_cast<const float4*>(
                        x + (size_t)pc * ICC + (c + 2) * CH + q4);
                }
            }
            __syncthreads();                  // tile(c+1) ready
        }

        // 16-cell burst: pure VALU + pipelined SMEM.
        // load cell j+1's weights BEFORE computing cell j; pin them AFTER,
        // so every s_load has ~34 VALU ops of latency cover.
        #pragma unroll
        for (int j = 0; j < CH; ++j) {
            Wc wn;
            if (j < CH - 1) wn = loadW(c * CH + j + 1, W1, b1, W2, b2);
            y = cellW(xi[j], y, wc);
            if (j < CH - 1) { pinW(wn); wc = wn; }
        }
    }

    // ---- tail: cells 192..194, then the final sigmoid cell (channel 195) ----
    {
        Wc w192 = loadW(192, W1, b1, W2, b2);
        Wc w193 = loadW(193, W1, b1, W2, b2);
        Wc w194 = loadW(194, W1, b1, W2, b2);
        y = cellW(tail.x, y, w192);
        y = cellW(tail.y, y, w193);
        y = cellW(tail.z, y, w194);
    }

    const float xf = tail.w;
    float h0 = fmaxf(fmaf(y, Wf1[6],  fmaf(xf, Wf1[0], bf1[0])), 0.0f);
    float h1 = fmaxf(fmaf(y, Wf1[7],  fmaf(xf, Wf1[1], bf1[1])), 0.0f);
    float h2 = fmaxf(fmaf(y, Wf1[8],  fmaf(xf, Wf1[2], bf1[2])), 0.0f);
    float h3 = fmaxf(fmaf(y, Wf1[9],  fmaf(xf, Wf1[3], bf1[3])), 0.0f);
    float h4 = fmaxf(fmaf(y, Wf1[10], fmaf(xf, Wf1[4], bf1[4])), 0.0f);
    float h5 = fmaxf(fmaf(y, Wf1[11], fmaf(xf, Wf1[5], bf1[5])), 0.0f);
    float s0 = fmaf(h0, Wf2[0], fmaf(h1, Wf2[1], bf2[0]));
    float s1 = fmaf(h2, Wf2[2], h3 * Wf2[3]);
    float s2 = fmaf(h4, Wf2[4], h5 * Wf2[5]);
    float t  = s0 + (s1 + s2);

    if (p < npoints)
        out[p] = 1.0f / (1.0f + __expf(-t));
}

extern "C" void kernel_launch(void* const* d_in, const int* in_sizes, int n_in,
                              void* d_out, int out_size, void* d_ws, size_t ws_size,
                              hipStream_t stream) {
    const float* x   = (const float*)d_in[0];
    const float* W1  = (const float*)d_in[1];
    const float* b1  = (const float*)d_in[2];
    const float* W2  = (const float*)d_in[3];
    const float* b2  = (const float*)d_in[4];
    const float* Wf1 = (const float*)d_in[5];
    const float* bf1 = (const float*)d_in[6];
    const float* Wf2 = (const float*)d_in[7];
    const float* bf2 = (const float*)d_in[8];
    float* out = (float*)d_out;

    const int npoints = out_size;                 // B*N = 262144
    const int grid = (npoints + BLK - 1) / BLK;   // 1024 blocks -> 4/CU
    rnn_kernel<<<grid, BLK, 0, stream>>>(x, W1, b1, W2, b2,
                                         Wf1, bf1, Wf2, bf2, out, npoints);
}

// Round 6
// 85.468 us; speedup vs baseline: 1.8484x; 1.0399x over previous
//
#include <hip/hip_runtime.h>
#include <math.h>

#define ICC 196   // channels per point
#define CH  32    // channels staged per phase
#define NPH 6     // 6*32 = 192 staged channels (cells 0..191); tail 4 direct
#define RS  258   // LDS row stride (dwords): writes 2 lanes/bank (free), reads 2-way (free)
#define BLK 256   // threads per block == points per block

// liveness pins: force value into a register at this point (defeats load sinking)
#define PINV(x) asm volatile("" : "+v"(x))
#define PINS(x) asm volatile("" : "+s"(x))

// one cell's weights in named scalar fields (wave-uniform -> SGPRs)
struct Wc {
    float a0,a1,a2,a3,a4,a5,a6,a7,a8,a9,a10,a11;  // W1 [2][6] row-major
    float c0,c1,c2,c3,c4,c5;                       // b1
    float d0,d1,d2,d3,d4,d5;                       // W2
    float e0;                                      // b2
};

__device__ __forceinline__ Wc loadW(int i,
    const float* __restrict__ W1, const float* __restrict__ b1,
    const float* __restrict__ W2, const float* __restrict__ b2)
{
    Wc w;
    const float* p = W1 + i * 12;
    w.a0=p[0]; w.a1=p[1]; w.a2=p[2];  w.a3=p[3];  w.a4=p[4];  w.a5=p[5];
    w.a6=p[6]; w.a7=p[7]; w.a8=p[8];  w.a9=p[9];  w.a10=p[10]; w.a11=p[11];
    const float* q = b1 + i * 6;
    w.c0=q[0]; w.c1=q[1]; w.c2=q[2]; w.c3=q[3]; w.c4=q[4]; w.c5=q[5];
    const float* r = W2 + i * 6;
    w.d0=r[0]; w.d1=r[1]; w.d2=r[2]; w.d3=r[3]; w.d4=r[4]; w.d5=r[5];
    w.e0 = b2[i];
    return w;
}

__device__ __forceinline__ void pinW(Wc& w) {
    PINS(w.a0); PINS(w.a1); PINS(w.a2);  PINS(w.a3);  PINS(w.a4);  PINS(w.a5);
    PINS(w.a6); PINS(w.a7); PINS(w.a8);  PINS(w.a9);  PINS(w.a10); PINS(w.a11);
    PINS(w.c0); PINS(w.c1); PINS(w.c2);  PINS(w.c3);  PINS(w.c4);  PINS(w.c5);
    PINS(w.d0); PINS(w.d1); PINS(w.d2);  PINS(w.d3);  PINS(w.d4);  PINS(w.d5);
    PINS(w.e0);
}

// z=[xi,y] -> Linear(2,6) -> ReLU -> Linear(6,1) -> ReLU, weights pre-pinned
__device__ __forceinline__ float cellW(float xi, float y, const Wc& w)
{
    float h0 = fmaxf(fmaf(y, w.a6,  fmaf(xi, w.a0, w.c0)), 0.0f);
    float h1 = fmaxf(fmaf(y, w.a7,  fmaf(xi, w.a1, w.c1)), 0.0f);
    float h2 = fmaxf(fmaf(y, w.a8,  fmaf(xi, w.a2, w.c2)), 0.0f);
    float h3 = fmaxf(fmaf(y, w.a9,  fmaf(xi, w.a3, w.c3)), 0.0f);
    float h4 = fmaxf(fmaf(y, w.a10, fmaf(xi, w.a4, w.c4)), 0.0f);
    float h5 = fmaxf(fmaf(y, w.a11, fmaf(xi, w.a5, w.c5)), 0.0f);
    float s0 = fmaf(h0, w.d0, fmaf(h1, w.d1, w.e0));
    float s1 = fmaf(h2, w.d2, h3 * w.d3);
    float s2 = fmaf(h4, w.d4, h5 * w.d5);
    return fmaxf(s0 + (s1 + s2), 0.0f);
}

__global__ __launch_bounds__(BLK, 4) void rnn_kernel(
    const float* __restrict__ x,    // [P, 196]
    const float* __restrict__ W1,   // [195, 2, 6]
    const float* __restrict__ b1,   // [195, 6]
    const float* __restrict__ W2,   // [195, 6]
    const float* __restrict__ b2,   // [195]
    const float* __restrict__ Wf1,  // [2, 6]
    const float* __restrict__ bf1,  // [6]
    const float* __restrict__ Wf2,  // [6]
    const float* __restrict__ bf2,  // [1]
    float* __restrict__ out,        // [P]
    int npoints)
{
    __shared__ float tile[CH * RS];   // transposed: tile[ch*RS + pt]

    const int tid = threadIdx.x;
    const int p0  = blockIdx.x * BLK;
    const int p   = p0 + tid;

    // staging map: thread t, sweep k -> row (t>>3)+32k, channels 4*(t&7)..+3
    // 8 consecutive lanes cover a 128B-contiguous run of one row -> coalesced.
    const int rl0 = tid >> 3;
    const int q4  = (tid & 7) * 4;

    float4 rA[8];   // next phase's staged chunk (32 VGPRs)

    // tail channels 192..195 of own point (oldest vmcnt entry, lands early)
    const int pc_self = (p < npoints) ? p : (npoints - 1);
    const float4 tail = *reinterpret_cast<const float4*>(
        x + (size_t)pc_self * ICC + 192);

    // ---- prologue: load+write phase 0, start loads for phase 1 ----
    #pragma unroll
    for (int k = 0; k < 8; ++k) {
        int rl = rl0 + 32 * k;
        int pc = p0 + rl; if (pc >= npoints) pc = npoints - 1;
        rA[k] = *reinterpret_cast<const float4*>(x + (size_t)pc * ICC + 0 * CH + q4);
    }
    #pragma unroll
    for (int k = 0; k < 8; ++k) {
        int rl = rl0 + 32 * k;
        tile[(q4 + 0) * RS + rl] = rA[k].x;
        tile[(q4 + 1) * RS + rl] = rA[k].y;
        tile[(q4 + 2) * RS + rl] = rA[k].z;
        tile[(q4 + 3) * RS + rl] = rA[k].w;
    }
    #pragma unroll
    for (int k = 0; k < 8; ++k) {
        int rl = rl0 + 32 * k;
        int pc = p0 + rl; if (pc >= npoints) pc = npoints - 1;
        rA[k] = *reinterpret_cast<const float4*>(x + (size_t)pc * ICC + 1 * CH + q4);
    }
    __builtin_amdgcn_sched_barrier(0);   // anchor: loads may not sink past here
    __syncthreads();

    float y = tile[0 * RS + tid];   // y0 = channel 0 of own point

    // ---- main loop ----
    #pragma unroll 1
    for (int c = 0; c < NPH; ++c) {
        // first cell's weights issued early (land during xi reads / barrier)
        Wc wc = loadW(c * CH, W1, b1, W2, b2);

        // slurp this phase's xi into VGPRs and PIN them there:
        // the compute burst below then has ZERO ds ops.
        float xi[CH];
        #pragma unroll
        for (int j = 0; j < CH; ++j)
            xi[j] = tile[j * RS + tid];       // lanes stride-1: 2-way = free
        #pragma unroll
        for (int j = 0; j < CH; ++j)
            PINV(xi[j]);

        pinW(wc);

        if (c < NPH - 1) {
            __syncthreads();                  // everyone's xi reads are done
            #pragma unroll
            for (int k = 0; k < 8; ++k) {     // write phase c+1 (rA long since landed)
                int rl = rl0 + 32 * k;
                tile[(q4 + 0) * RS + rl] = rA[k].x;
                tile[(q4 + 1) * RS + rl] = rA[k].y;
                tile[(q4 + 2) * RS + rl] = rA[k].z;
                tile[(q4 + 3) * RS + rl] = rA[k].w;
            }
            if (c < NPH - 2) {                // issue phase c+2 loads (fly over burst)
                #pragma unroll
                for (int k = 0; k < 8; ++k) {
                    int rl = rl0 + 32 * k;
                    int pc = p0 + rl; if (pc >= npoints) pc = npoints - 1;
                    rA[k] = *reinterpret_cast<const float4*>(
                        x + (size_t)pc * ICC + (c + 2) * CH + q4);
                }
            }
            __builtin_amdgcn_sched_barrier(0); // anchor: issue stays HERE, wait stays late
            __syncthreads();                   // tile(c+1) ready
        }

        // 32-cell burst: pure VALU + 1-deep pinned SMEM weight pipeline.
        #pragma unroll
        for (int j = 0; j < CH; ++j) {
            Wc wn;
            if (j < CH - 1) wn = loadW(c * CH + j + 1, W1, b1, W2, b2);
            y = cellW(xi[j], y, wc);
            if (j < CH - 1) { pinW(wn); wc = wn; }
        }
    }

    // ---- tail: cells 192..194, then the final sigmoid cell (channel 195) ----
    {
        Wc w192 = loadW(192, W1, b1, W2, b2);
        Wc w193 = loadW(193, W1, b1, W2, b2);
        Wc w194 = loadW(194, W1, b1, W2, b2);
        y = cellW(tail.x, y, w192);
        y = cellW(tail.y, y, w193);
        y = cellW(tail.z, y, w194);
    }

    const float xf = tail.w;
    float h0 = fmaxf(fmaf(y, Wf1[6],  fmaf(xf, Wf1[0], bf1[0])), 0.0f);
    float h1 = fmaxf(fmaf(y, Wf1[7],  fmaf(xf, Wf1[1], bf1[1])), 0.0f);
    float h2 = fmaxf(fmaf(y, Wf1[8],  fmaf(xf, Wf1[2], bf1[2])), 0.0f);
    float h3 = fmaxf(fmaf(y, Wf1[9],  fmaf(xf, Wf1[3], bf1[3])), 0.0f);
    float h4 = fmaxf(fmaf(y, Wf1[10], fmaf(xf, Wf1[4], bf1[4])), 0.0f);
    float h5 = fmaxf(fmaf(y, Wf1[11], fmaf(xf, Wf1[5], bf1[5])), 0.0f);
    float s0 = fmaf(h0, Wf2[0], fmaf(h1, Wf2[1], bf2[0]));
    float s1 = fmaf(h2, Wf2[2], h3 * Wf2[3]);
    float s2 = fmaf(h4, Wf2[4], h5 * Wf2[5]);
    float t  = s0 + (s1 + s2);

    if (p < npoints)
        out[p] = 1.0f / (1.0f + __expf(-t));
}

extern "C" void kernel_launch(void* const* d_in, const int* in_sizes, int n_in,
                              void* d_out, int out_size, void* d_ws, size_t ws_size,
                              hipStream_t stream) {
    const float* x   = (const float*)d_in[0];
    const float* W1  = (const float*)d_in[1];
    const float* b1  = (const float*)d_in[2];
    const float* W2  = (const float*)d_in[3];
    const float* b2  = (const float*)d_in[4];
    const float* Wf1 = (const float*)d_in[5];
    const float* bf1 = (const float*)d_in[6];
    const float* Wf2 = (const float*)d_in[7];
    const float* bf2 = (const float*)d_in[8];
    float* out = (float*)d_out;

    const int npoints = out_size;                 // B*N = 262144
    const int grid = (npoints + BLK - 1) / BLK;   // 1024 blocks -> 4/CU
    rnn_kernel<<<grid, BLK, 0, stream>>>(x, W1, b1, W2, b2,
                                         Wf1, bf1, Wf2, bf2, out, npoints);
}